// Round 13
// baseline (214.333 us; speedup 1.0000x reference)
//
#include <hip/hip_runtime.h>
#include <stdint.h>

#define T_TOK 2048
#define HDIM  2048
#define FDIM  1024
#define NEXP  8

#define BM   128
#define BK   64
#define NTHR 256
#define MT_MAX 16                 // 2048 / BM
#define BN1  64
#define BN2  128
#define NT1 (FDIM / BN1)          // 16
#define NT2 (HDIM / BN2)          // 16
#define NK1 (HDIM / BK)           // 32
#define NK2 (FDIM / BK)           // 16
#define GRID2K (NEXP * MT_MAX * NT2)  // 2048 (gemm2)
#define TILE_E 4096               // elems per 64x64 bf16 tile (8 KB)
#define SMEM2 65536               // mega2/gemm LDS (double-buffered)

typedef unsigned short u16;
typedef __attribute__((ext_vector_type(16))) float f32x16;
typedef __attribute__((ext_vector_type(8))) short bf16x8;

__device__ __forceinline__ u16 f2bf(float f) {
  uint32_t u = __float_as_uint(f);
  u += 0x7FFFu + ((u >> 16) & 1u);   // RNE
  return (u16)(u >> 16);
}

__device__ __forceinline__ uint32_t pack2(float lo, float hi) {
  return (uint32_t)f2bf(lo) | ((uint32_t)f2bf(hi) << 16);
}

__device__ __forceinline__ void glds16(const u16* src, u16* dst) {
  __builtin_amdgcn_global_load_lds(
      (const __attribute__((address_space(1))) uint32_t*)src,
      (__attribute__((address_space(3))) uint32_t*)dst, 16, 0, 0);
}

// ---------------------------------------------------------------------------
// Routing (order-invariant y; see R2 notes).
// ---------------------------------------------------------------------------
__global__ void route1_kernel(const float* __restrict__ logits,
                              int* __restrict__ tok_e, float* __restrict__ tok_w,
                              int* __restrict__ counts) {
  __shared__ int lcnt[NEXP];
  const int tid = threadIdx.x;
  const int t = blockIdx.x * 256 + tid;
  if (tid < NEXP) lcnt[tid] = 0;
  __syncthreads();
  float l[NEXP];
#pragma unroll
  for (int e = 0; e < NEXP; ++e) l[e] = logits[t * NEXP + e];
  float m = l[0];
#pragma unroll
  for (int e = 1; e < NEXP; ++e) m = fmaxf(m, l[e]);
  float p[NEXP]; float s = 0.f;
#pragma unroll
  for (int e = 0; e < NEXP; ++e) { p[e] = __expf(l[e] - m); s += p[e]; }
  float inv = 1.f / s;
  int i0 = 0; float p0 = p[0];
#pragma unroll
  for (int e = 1; e < NEXP; ++e) if (p[e] > p0) { p0 = p[e]; i0 = e; }
  int i1 = -1; float p1 = -1.f;
#pragma unroll
  for (int e = 0; e < NEXP; ++e) if (e != i0 && p[e] > p1) { p1 = p[e]; i1 = e; }
  tok_e[t] = i0 | (i1 << 8);
  tok_w[t * 2]     = p0 * inv;
  tok_w[t * 2 + 1] = p1 * inv;
  atomicAdd(&lcnt[i0], 1);
  atomicAdd(&lcnt[i1], 1);
  __syncthreads();
  if (tid < NEXP) atomicAdd(&counts[tid], lcnt[tid]);
}

__global__ void route2_kernel(const int* __restrict__ counts,
                              int* __restrict__ offsets, int* __restrict__ cursor) {
  if (threadIdx.x == 0) {
    int s = 0;
    for (int e = 0; e < NEXP; ++e) { offsets[e] = s; cursor[e] = s; s += counts[e]; }
    offsets[NEXP] = s;
  }
}

__global__ void route3_kernel(const int* __restrict__ tok_e, const float* __restrict__ tok_w,
                              int* __restrict__ cursor,
                              int* __restrict__ token_list, float* __restrict__ slot_w) {
  __shared__ int lcnt[NEXP], lbase[NEXP];
  const int tid = threadIdx.x;
  const int t = blockIdx.x * 256 + tid;
  if (tid < NEXP) lcnt[tid] = 0;
  __syncthreads();
  int ee = tok_e[t];
  int e0 = ee & 255, e1 = ee >> 8;
  int li0 = atomicAdd(&lcnt[e0], 1);
  int li1 = atomicAdd(&lcnt[e1], 1);
  __syncthreads();
  if (tid < NEXP) lbase[tid] = atomicAdd(&cursor[tid], lcnt[tid]);
  __syncthreads();
  int s0 = lbase[e0] + li0;
  int s1 = lbase[e1] + li1;
  token_list[s0] = t; slot_w[s0] = tok_w[t * 2];
  token_list[s1] = t; slot_w[s1] = tok_w[t * 2 + 1];
}

// ---------------------------------------------------------------------------
// Weight conversion block: linear-read (64 KB seq), contiguous 2 KB runs out.
// Blob intra-tile order: [kq4][n64][k16], halves swapped by s(n)=(n>>2)&1.
// ---------------------------------------------------------------------------
__device__ __forceinline__ void wconv_block(const float* __restrict__ src,
                                            u16* __restrict__ dstb,
                                            int C, int NT, int NKT,
                                            int e, int r0, int c0, uint32_t* L) {
  const int t = threadIdx.x;
  const int p  = t >> 5;        // row-pair 0..7
  const int ln = t & 31;
  const float* row0 = src + (size_t)(r0 + 2 * p) * C + c0;
  const float* row1 = row0 + C;
  float4 f0[8], f1[8];
#pragma unroll
  for (int j = 0; j < 8; ++j) f0[j] = *(const float4*)(row0 + j * 128 + ln * 4);
#pragma unroll
  for (int j = 0; j < 8; ++j) f1[j] = *(const float4*)(row1 + j * 128 + ln * 4);
#pragma unroll
  for (int j = 0; j < 8; ++j) {
    int n = j * 128 + ln * 4;
    L[(n + 0) * 9 + p] = pack2(f0[j].x, f1[j].x);
    L[(n + 1) * 9 + p] = pack2(f0[j].y, f1[j].y);
    L[(n + 2) * 9 + p] = pack2(f0[j].z, f1[j].z);
    L[(n + 3) * 9 + p] = pack2(f0[j].w, f1[j].w);
  }
  __syncthreads();
  const int kt = r0 >> 6, kq = (r0 >> 4) & 3;
#pragma unroll
  for (int i = 0; i < 4; ++i) {
    int n = t * 4 + i;
    const uint32_t* a = &L[n * 9];
    uint4 lo = {a[0], a[1], a[2], a[3]};
    uint4 hi = {a[4], a[5], a[6], a[7]};
    int ng = c0 + n;
    int s = (n >> 2) & 1;
    u16* tb = dstb + (((size_t)e * NT + (ng >> 6)) * NKT + kt) * TILE_E
                   + kq * 1024 + (n & 63) * 16;
    *(uint4*)(tb + s * 8)       = lo;
    *(uint4*)(tb + (s ^ 1) * 8) = hi;
  }
}

// ---------------------------------------------------------------------------
// MEGA1: bid<2048: w1/w3 conversion; 2048..2304: x cvt; 2304..2560: y zero.
// ---------------------------------------------------------------------------
__global__ __launch_bounds__(256, 3)
void mega1_kernel(const float* __restrict__ w1, const float* __restrict__ w3,
                  u16* __restrict__ w1b, u16* __restrict__ w3b,
                  const float4* __restrict__ x, ushort4* __restrict__ xb,
                  float4* __restrict__ y4) {
  __shared__ __align__(16) uint8_t smem[36864];
  const int bid = blockIdx.x;
  const int t = threadIdx.x;
  if (bid < 2048) {
    const int m = bid >> 10;
    const int r = bid & 1023;
    const int e = r >> 7;
    const int g = r & 127;
    const size_t msz = (size_t)HDIM * FDIM;
    wconv_block((m ? w3 : w1) + (size_t)e * msz, m ? w3b : w1b,
                FDIM, 16, 32, e, g * 16, 0, (uint32_t*)smem);
  } else if (bid < 2304) {
    int i = (bid - 2048) * 256 + t;
#pragma unroll
    for (int r = 0; r < 16; ++r, i += 65536) {
      float4 v = x[i];
      ushort4 o;
      o.x = f2bf(v.x); o.y = f2bf(v.y); o.z = f2bf(v.z); o.w = f2bf(v.w);
      xb[i] = o;
    }
  } else {
    int i = (bid - 2304) * 256 + t;
    float4 z = {0.f, 0.f, 0.f, 0.f};
#pragma unroll
    for (int r = 0; r < 16; ++r, i += 65536) y4[i] = z;
  }
}

// ---------------------------------------------------------------------------
// MEGA2: bid<1024: w2 conversion (concurrent with gemm1); bid>=1024: gemm1.
// gemm1: double-buffered 2-phase with COMPILE-TIME buffer names (K-loop
// unrolled x2): FRAGS(cur) -> issue stage(next) -> MFMA -> ONE barrier.
// Stage latency hides under reads+MFMA; barrier count halved.
// ---------------------------------------------------------------------------
__global__ __launch_bounds__(256, 2)
void mega2_kernel(const float* __restrict__ w2, u16* __restrict__ w2b,
                  const u16* __restrict__ Xb,
                  const u16* __restrict__ w1b, const u16* __restrict__ w3b,
                  const int* __restrict__ token_list,
                  const float* __restrict__ slot_w,
                  const int* __restrict__ counts,
                  const int* __restrict__ offsets,
                  u16* __restrict__ act) {
  __shared__ __align__(16) uint8_t smem[SMEM2];
  const int bid = blockIdx.x;
  if (bid < 1024) {
    const int e = bid >> 7;
    const int r = bid & 127;
    const int g = r & 63;
    const int half = r >> 6;
    wconv_block(w2 + (size_t)e * HDIM * FDIM, w2b,
                HDIM, 32, 16, e, g * 16, half * 1024, (uint32_t*)smem);
    return;
  }
  const int gb = bid - 1024;
  const int e  = gb >> 8;
  const int mt = (gb >> 4) & 15;
  const int nt = gb & 15;
  const int cnt = counts[e];
  if (mt * BM >= cnt) return;
  const int off = offsets[e];
  const int tid  = threadIdx.x;
  const int lane = tid & 63;
  const int wid  = tid >> 6;
  const int wr = wid >> 1;
  const int wc = wid & 1;

  u16* A0  = (u16*)smem;                 // 16 KB
  u16* A1  = (u16*)(smem + 16384);       // 16 KB
  u16* B10 = (u16*)(smem + 32768);       // 8 KB
  u16* B30 = (u16*)(smem + 40960);       // 8 KB
  u16* B11 = (u16*)(smem + 49152);       // 8 KB
  u16* B31 = (u16*)(smem + 57344);       // 8 KB

  const u16* a_src[4];
#pragma unroll
  for (int i = 0; i < 4; ++i) {
    int row = (wid * 4 + i) * 8 + (lane >> 3);
    int mg = mt * BM + row;
    int mc = (mg < cnt) ? mg : (cnt - 1);
    int tok = token_list[off + mc];
    a_src[i] = Xb + (size_t)tok * HDIM + (((lane & 7) ^ (row & 7)) * 8);
  }
  const u16* b1_src[2];
  const u16* b3_src[2];
  {
    size_t tbase = ((size_t)(e * 16 + nt) * 32) * TILE_E;
#pragma unroll
    for (int i = 0; i < 2; ++i) {
      int c = wid * 2 + i;
      b1_src[i] = w1b + tbase + c * 512 + lane * 8;
      b3_src[i] = w3b + tbase + c * 512 + lane * 8;
    }
  }

  f32x16 accg[2] = {};
  f32x16 accu[2] = {};
  bf16x8 af[2][4], bg[4], bu[4];

#define STAGE1(Ab, B1b, B3b, T)                                          \
  { const size_t ks = (size_t)(T) * BK;                                  \
    const size_t kb = (size_t)(T) * TILE_E;                              \
    _Pragma("unroll")                                                    \
    for (int i = 0; i < 4; ++i) glds16(a_src[i] + ks, &Ab[(wid * 4 + i) * 512]); \
    _Pragma("unroll")                                                    \
    for (int i = 0; i < 2; ++i) {                                        \
      glds16(b1_src[i] + kb, &B1b[(wid * 2 + i) * 512]);                 \
      glds16(b3_src[i] + kb, &B3b[(wid * 2 + i) * 512]);                 \
    } }

#define FRAGS1(Ab, B1b, B3b)                                             \
  { _Pragma("unroll")                                                    \
    for (int m = 0; m < 2; ++m) {                                        \
      int R = wr * 64 + m * 32 + (lane & 31);                            \
      _Pragma("unroll")                                                  \
      for (int kk = 0; kk < 4; ++kk) {                                   \
        int gl = kk * 2 + (lane >> 5);                                   \
        af[m][kk] = *(const bf16x8*)&Ab[R * BK + ((gl ^ (R & 7)) * 8)];  \
      }                                                                  \
    }                                                                    \
    { int R = wc * 32 + (lane & 31);                                     \
      int base = R * 16 + (((lane >> 5) ^ ((R >> 2) & 1)) * 8);          \
      _Pragma("unroll")                                                  \
      for (int kk = 0; kk < 4; ++kk) {                                   \
        bg[kk] = *(const bf16x8*)&B1b[base + kk * 1024];                 \
        bu[kk] = *(const bf16x8*)&B3b[base + kk * 1024];                 \
      } } }

#define MFMA1                                                            \
  { _Pragma("unroll")                                                    \
    for (int m = 0; m < 2; ++m)                                          \
      _Pragma("unroll")                                                  \
      for (int kk = 0; kk < 4; ++kk) {                                   \
        accg[m] = __builtin_amdgcn_mfma_f32_32x32x16_bf16(af[m][kk], bg[kk], accg[m], 0, 0, 0); \
        accu[m] = __builtin_amdgcn_mfma_f32_32x32x16_bf16(af[m][kk], bu[kk], accu[m], 0, 0, 0); \
      } }

  STAGE1(A0, B10, B30, 0);
  __syncthreads();                 // tile 0 resident

#pragma unroll 1
  for (int t = 0; t < NK1; t += 2) {
    // phase A: compute buf0, stage t+1 -> buf1
    FRAGS1(A0, B10, B30);
    STAGE1(A1, B11, B31, t + 1);   // in flight under MFMA; drained at barrier
    MFMA1;
    __syncthreads();
    // phase B: compute buf1, stage t+2 -> buf0
    FRAGS1(A1, B11, B31);
    if (t + 2 < NK1) STAGE1(A0, B10, B30, t + 2);
    MFMA1;
    __syncthreads();
  }
#undef STAGE1
#undef FRAGS1
#undef MFMA1

  // epilogue. 32x32 C/D: col=lane&31, row=(reg&3)+8*(reg>>2)+4*(lane>>5)
  const int fcol = nt * BN1 + wc * 32 + (lane & 31);
#pragma unroll
  for (int m = 0; m < 2; ++m) {
    int base = mt * BM + wr * 64 + m * 32 + 4 * (lane >> 5);
#pragma unroll
    for (int reg = 0; reg < 16; ++reg) {
      int mg = base + (reg & 3) + 8 * (reg >> 2);
      if (mg < cnt) {
        int slot = off + mg;
        float wgt = slot_w[slot];
        float g = accg[m][reg];
        float u = accu[m][reg];
        float sv = g / (1.f + __expf(-g));
        act[(size_t)slot * FDIM + fcol] = f2bf(sv * u * wgt);
      }
    }
  }
}

// ---------------------------------------------------------------------------
// GEMM2: y[token,h] += act[slot,:] @ w2 (blob). BM=128 BN=128 BK=64, wave
// tile 64x64. Same dbuf 2-phase named-buffer schedule.
// ---------------------------------------------------------------------------
__global__ __launch_bounds__(NTHR, 2)
void gemm2_kernel(const u16* __restrict__ act,
                  const u16* __restrict__ w2b,   // tiled [e][nt32][kt16][4096]
                  const int* __restrict__ token_list,
                  const int* __restrict__ counts,
                  const int* __restrict__ offsets,
                  float* __restrict__ y) {
  const int bid = blockIdx.x;
  const int e  = bid >> 8;
  const int mt = (bid >> 4) & 15;
  const int nt = bid & 15;
  const int cnt = counts[e];
  if (mt * BM >= cnt) return;
  const int off = offsets[e];
  const int tid  = threadIdx.x;
  const int lane = tid & 63;
  const int wid  = tid >> 6;
  const int wr = wid >> 1;
  const int wc = wid & 1;

  __shared__ u16 A0[BM * BK];     // 16 KB
  __shared__ u16 A1[BM * BK];
  __shared__ u16 B0[BN2 * BK];    // 16 KB
  __shared__ u16 B1[BN2 * BK];

  const u16* a_src[4];
  const u16* b_src[4];
#pragma unroll
  for (int i = 0; i < 4; ++i) {
    int row = (wid * 4 + i) * 8 + (lane >> 3);
    int mg = mt * BM + row;
    int mc = (mg < cnt) ? mg : (cnt - 1);
    a_src[i] = act + (size_t)(off + mc) * FDIM + (((lane & 7) ^ (row & 7)) * 8);
    int c = wid * 4 + i;
    size_t tbase = ((size_t)(e * 32 + nt * 2 + (c >> 3)) * 16) * TILE_E;
    b_src[i] = w2b + tbase + (c & 7) * 512 + lane * 8;
  }

  f32x16 acc[2][2] = {};
  bf16x8 af[2][4], bb[2][4];

#define STAGE2(Ab, Bb, T)                                                \
  { const size_t ks = (size_t)(T) * BK;                                  \
    const size_t kb = (size_t)(T) * TILE_E;                              \
    _Pragma("unroll")                                                    \
    for (int i = 0; i < 4; ++i) {                                        \
      glds16(a_src[i] + ks, &Ab[(wid * 4 + i) * 512]);                   \
      glds16(b_src[i] + kb, &Bb[(wid * 4 + i) * 512]);                   \
    } }

#define FRAGS2(Ab, Bb)                                                   \
  { _Pragma("unroll")                                                    \
    for (int m = 0; m < 2; ++m) {                                        \
      int R = wr * 64 + m * 32 + (lane & 31);                            \
      _Pragma("unroll")                                                  \
      for (int kk = 0; kk < 4; ++kk) {                                   \
        int gl = kk * 2 + (lane >> 5);                                   \
        af[m][kk] = *(const bf16x8*)&Ab[R * BK + ((gl ^ (R & 7)) * 8)];  \
      }                                                                  \
    }                                                                    \
    _Pragma("unroll")                                                    \
    for (int n = 0; n < 2; ++n) {                                        \
      int R = wc * 64 + n * 32 + (lane & 31);                            \
      int base = (R >> 6) * TILE_E + (R & 63) * 16 + (((lane >> 5) ^ ((R >> 2) & 1)) * 8); \
      _Pragma("unroll")                                                  \
      for (int kk = 0; kk < 4; ++kk)                                     \
        bb[n][kk] = *(const bf16x8*)&Bb[base + kk * 1024];               \
    } }

#define MFMA2                                                            \
  { _Pragma("unroll")                                                    \
    for (int kk = 0; kk < 4; ++kk)                                       \
      _Pragma("unroll")                                                  \
      for (int m = 0; m < 2; ++m)                                        \
        _Pragma("unroll")                                                \
        for (int n = 0; n < 2; ++n)                                      \
          acc[m][n] = __builtin_amdgcn_mfma_f32_32x32x16_bf16(af[m][kk], bb[n][kk], acc[m][n], 0, 0, 0); }

  STAGE2(A0, B0, 0);
  __syncthreads();

#pragma unroll 1
  for (int t = 0; t < NK2; t += 2) {
    FRAGS2(A0, B0);
    STAGE2(A1, B1, t + 1);
    MFMA2;
    __syncthreads();
    FRAGS2(A1, B1);
    if (t + 2 < NK2) STAGE2(A0, B0, t + 2);
    MFMA2;
    __syncthreads();
  }
#undef STAGE2
#undef FRAGS2
#undef MFMA2

#pragma unroll
  for (int m = 0; m < 2; ++m) {
    int base = mt * BM + wr * 64 + m * 32 + 4 * (lane >> 5);
#pragma unroll
    for (int reg = 0; reg < 16; ++reg) {
      int mg = base + (reg & 3) + 8 * (reg >> 2);
      if (mg < cnt) {
        int slot = off + mg;
        int tok = token_list[slot];
#pragma unroll
        for (int n = 0; n < 2; ++n) {
          int hcol = nt * BN2 + wc * 64 + n * 32 + (lane & 31);
          unsafeAtomicAdd(y + (size_t)tok * HDIM + hcol, acc[m][n][reg]);
        }
      }
    }
  }
}

// ---------------------------------------------------------------------------
extern "C" void kernel_launch(void* const* d_in, const int* in_sizes, int n_in,
                              void* d_out, int out_size, void* d_ws, size_t ws_size,
                              hipStream_t stream) {
  (void)in_sizes; (void)n_in; (void)out_size; (void)ws_size;
  const float* hs     = (const float*)d_in[0];
  const float* logits = (const float*)d_in[1];
  const float* w1     = (const float*)d_in[2];
  const float* w3     = (const float*)d_in[3];
  const float* w2     = (const float*)d_in[4];
  float* y = (float*)d_out;

  uint8_t* ws = (uint8_t*)d_ws;
  int*   token_list = (int*)(ws);
  float* slot_w     = (float*)(ws + (16 << 10));
  int*   counts     = (int*)(ws + (32 << 10));
  int*   offsets    = (int*)(ws + (32 << 10) + 128);
  int*   cursor     = (int*)(ws + (32 << 10) + 256);
  int*   tok_e      = (int*)(ws + (33 << 10));
  float* tok_w      = (float*)(ws + (42 << 10));
  const size_t MB = 1 << 20;
  u16*   Xb  = (u16*)(ws + (64 << 10));                 // 8 MB
  u16*   act = (u16*)(ws + (64 << 10) + 8 * MB);        // 8 MB
  u16*   w1b = (u16*)(ws + (64 << 10) + 16 * MB);       // 32 MB tiled
  u16*   w3b = (u16*)(ws + (64 << 10) + 48 * MB);       // 32 MB tiled
  u16*   w2b = (u16*)(ws + (64 << 10) + 80 * MB);       // 32 MB tiled

  hipMemsetAsync(counts, 0, NEXP * sizeof(int), stream);
  route1_kernel<<<T_TOK / 256, 256, 0, stream>>>(logits, tok_e, tok_w, counts);
  route2_kernel<<<1, 64, 0, stream>>>(counts, offsets, cursor);
  route3_kernel<<<T_TOK / 256, 256, 0, stream>>>(tok_e, tok_w, cursor, token_list, slot_w);
  mega1_kernel<<<2560, 256, 0, stream>>>(w1, w3, w1b, w3b,
                                         (const float4*)hs, (ushort4*)Xb, (float4*)y);
  mega2_kernel<<<3072, 256, 0, stream>>>(w2, w2b, Xb, w1b, w3b,
                                         token_list, slot_w, counts, offsets, act);
  gemm2_kernel<<<GRID2K, NTHR, 0, stream>>>(act, w2b, token_list, counts, offsets, y);
}

// Round 14
// 198.452 us; speedup vs baseline: 1.0800x; 1.0800x over previous
//
#include <hip/hip_runtime.h>
#include <stdint.h>

#define T_TOK 2048
#define HDIM  2048
#define FDIM  1024
#define NEXP  8

#define BM   128
#define BK   64
#define NTHR 256
#define MT_MAX 16                 // 2048 / BM
#define BN1  64
#define BN2  128
#define NT1 (FDIM / BN1)          // 16
#define NT2 (HDIM / BN2)          // 16
#define NK1 (HDIM / BK)           // 32
#define NK2 (FDIM / BK)           // 16
#define GRID2K (NEXP * MT_MAX * NT2)  // 2048 (gemm2)
#define TILE_E 4096               // elems per 64x64 bf16 tile (8 KB)

typedef unsigned short u16;
typedef __attribute__((ext_vector_type(16))) float f32x16;
typedef __attribute__((ext_vector_type(8))) short bf16x8;

__device__ __forceinline__ u16 f2bf(float f) {
  uint32_t u = __float_as_uint(f);
  u += 0x7FFFu + ((u >> 16) & 1u);   // RNE
  return (u16)(u >> 16);
}

__device__ __forceinline__ uint32_t pack2(float lo, float hi) {
  return (uint32_t)f2bf(lo) | ((uint32_t)f2bf(hi) << 16);
}

__device__ __forceinline__ void glds16(const u16* src, u16* dst) {
  __builtin_amdgcn_global_load_lds(
      (const __attribute__((address_space(1))) uint32_t*)src,
      (__attribute__((address_space(3))) uint32_t*)dst, 16, 0, 0);
}

// ---------------------------------------------------------------------------
// Routing (order-invariant y; see R2 notes).
// ---------------------------------------------------------------------------
__global__ void route1_kernel(const float* __restrict__ logits,
                              int* __restrict__ tok_e, float* __restrict__ tok_w,
                              int* __restrict__ counts) {
  __shared__ int lcnt[NEXP];
  const int tid = threadIdx.x;
  const int t = blockIdx.x * 256 + tid;
  if (tid < NEXP) lcnt[tid] = 0;
  __syncthreads();
  float l[NEXP];
#pragma unroll
  for (int e = 0; e < NEXP; ++e) l[e] = logits[t * NEXP + e];
  float m = l[0];
#pragma unroll
  for (int e = 1; e < NEXP; ++e) m = fmaxf(m, l[e]);
  float p[NEXP]; float s = 0.f;
#pragma unroll
  for (int e = 0; e < NEXP; ++e) { p[e] = __expf(l[e] - m); s += p[e]; }
  float inv = 1.f / s;
  int i0 = 0; float p0 = p[0];
#pragma unroll
  for (int e = 1; e < NEXP; ++e) if (p[e] > p0) { p0 = p[e]; i0 = e; }
  int i1 = -1; float p1 = -1.f;
#pragma unroll
  for (int e = 0; e < NEXP; ++e) if (e != i0 && p[e] > p1) { p1 = p[e]; i1 = e; }
  tok_e[t] = i0 | (i1 << 8);
  tok_w[t * 2]     = p0 * inv;
  tok_w[t * 2 + 1] = p1 * inv;
  atomicAdd(&lcnt[i0], 1);
  atomicAdd(&lcnt[i1], 1);
  __syncthreads();
  if (tid < NEXP) atomicAdd(&counts[tid], lcnt[tid]);
}

__global__ void route2_kernel(const int* __restrict__ counts,
                              int* __restrict__ offsets, int* __restrict__ cursor) {
  if (threadIdx.x == 0) {
    int s = 0;
    for (int e = 0; e < NEXP; ++e) { offsets[e] = s; cursor[e] = s; s += counts[e]; }
    offsets[NEXP] = s;
  }
}

__global__ void route3_kernel(const int* __restrict__ tok_e, const float* __restrict__ tok_w,
                              int* __restrict__ cursor,
                              int* __restrict__ token_list, float* __restrict__ slot_w) {
  __shared__ int lcnt[NEXP], lbase[NEXP];
  const int tid = threadIdx.x;
  const int t = blockIdx.x * 256 + tid;
  if (tid < NEXP) lcnt[tid] = 0;
  __syncthreads();
  int ee = tok_e[t];
  int e0 = ee & 255, e1 = ee >> 8;
  int li0 = atomicAdd(&lcnt[e0], 1);
  int li1 = atomicAdd(&lcnt[e1], 1);
  __syncthreads();
  if (tid < NEXP) lbase[tid] = atomicAdd(&cursor[tid], lcnt[tid]);
  __syncthreads();
  int s0 = lbase[e0] + li0;
  int s1 = lbase[e1] + li1;
  token_list[s0] = t; slot_w[s0] = tok_w[t * 2];
  token_list[s1] = t; slot_w[s1] = tok_w[t * 2 + 1];
}

// ---------------------------------------------------------------------------
// MEGA1-lite: bid<256: x fp32->bf16; else: y zero-fill.
// ---------------------------------------------------------------------------
__global__ __launch_bounds__(256)
void mega1_kernel(const float4* __restrict__ x, ushort4* __restrict__ xb,
                  float4* __restrict__ y4) {
  const int bid = blockIdx.x;
  const int t = threadIdx.x;
  if (bid < 256) {
    int i = bid * 256 + t;
#pragma unroll
    for (int r = 0; r < 16; ++r, i += 65536) {
      float4 v = x[i];
      ushort4 o;
      o.x = f2bf(v.x); o.y = f2bf(v.y); o.z = f2bf(v.z); o.w = f2bf(v.w);
      xb[i] = o;
    }
  } else {
    int i = (bid - 256) * 256 + t;
    float4 z = {0.f, 0.f, 0.f, 0.f};
#pragma unroll
    for (int r = 0; r < 16; ++r, i += 65536) y4[i] = z;
  }
}

// ---------------------------------------------------------------------------
// w2 conversion block (R12-proven): linear 64 KB read, contiguous 2 KB runs
// out; blob intra-tile order [kq4][n64][k16], halves swapped by s(n)=(n>>2)&1.
// ---------------------------------------------------------------------------
__device__ __forceinline__ void wconv_block(const float* __restrict__ src,
                                            u16* __restrict__ dstb,
                                            int C, int NT, int NKT,
                                            int e, int r0, int c0, uint32_t* L) {
  const int t = threadIdx.x;
  const int p  = t >> 5;        // row-pair 0..7
  const int ln = t & 31;
  const float* row0 = src + (size_t)(r0 + 2 * p) * C + c0;
  const float* row1 = row0 + C;
  float4 f0[8], f1[8];
#pragma unroll
  for (int j = 0; j < 8; ++j) f0[j] = *(const float4*)(row0 + j * 128 + ln * 4);
#pragma unroll
  for (int j = 0; j < 8; ++j) f1[j] = *(const float4*)(row1 + j * 128 + ln * 4);
#pragma unroll
  for (int j = 0; j < 8; ++j) {
    int n = j * 128 + ln * 4;
    L[(n + 0) * 9 + p] = pack2(f0[j].x, f1[j].x);
    L[(n + 1) * 9 + p] = pack2(f0[j].y, f1[j].y);
    L[(n + 2) * 9 + p] = pack2(f0[j].z, f1[j].z);
    L[(n + 3) * 9 + p] = pack2(f0[j].w, f1[j].w);
  }
  __syncthreads();
  const int kt = r0 >> 6, kq = (r0 >> 4) & 3;
#pragma unroll
  for (int i = 0; i < 4; ++i) {
    int n = t * 4 + i;
    const uint32_t* a = &L[n * 9];
    uint4 lo = {a[0], a[1], a[2], a[3]};
    uint4 hi = {a[4], a[5], a[6], a[7]};
    int ng = c0 + n;
    int s = (n >> 2) & 1;
    u16* tb = dstb + (((size_t)e * NT + (ng >> 6)) * NKT + kt) * TILE_E
                   + kq * 1024 + (n & 63) * 16;
    *(uint4*)(tb + s * 8)       = lo;
    *(uint4*)(tb + (s ^ 1) * 8) = hi;
  }
}

// ---------------------------------------------------------------------------
// MEGA2: bid<1024: w2 conversion (concurrent with gemm1); bid>=1024: gemm1
// with FUSED in-loop w1/w3 fp32->bf16 conversion.
// gemm1 schedule (R5/R12-proven 2-barrier single-buffer, extended):
//   [bar1] issue B1 fp32 loads(t+1) -> FRAGS(t) -> [bar2] -> glds A(t+1)
//   -> MFMA half1 -> cvt+write B1(t+1), issue B3 loads(t+1)
//   -> MFMA half2 -> cvt+write B3(t+1) -> loop.
// <=4 float4 live; all LDS writes after bar2 (no hazard); B-load latency
// hides under FRAGS+MFMA. B LDS layout [n][granule^S(n)], S(n)=((n>>3)^n)&7:
// writes 2-way-free, frag reads 4-way (status quo), 16B-aligned.
// ---------------------------------------------------------------------------
__global__ __launch_bounds__(256, 3)
void mega2_kernel(const float* __restrict__ w2, u16* __restrict__ w2b,
                  const u16* __restrict__ Xb,
                  const float* __restrict__ w1, const float* __restrict__ w3,
                  const int* __restrict__ token_list,
                  const float* __restrict__ slot_w,
                  const int* __restrict__ counts,
                  const int* __restrict__ offsets,
                  u16* __restrict__ act) {
  __shared__ __align__(16) uint8_t smem[36864];
  const int bid = blockIdx.x;
  if (bid < 1024) {
    const int e = bid >> 7;
    const int r = bid & 127;
    const int g = r & 63;
    const int half = r >> 6;
    wconv_block(w2 + (size_t)e * HDIM * FDIM, w2b,
                HDIM, 32, 16, e, g * 16, half * 1024, (uint32_t*)smem);
    return;
  }
  const int gb = bid - 1024;
  const int e  = gb >> 8;
  const int mt = (gb >> 4) & 15;
  const int nt = gb & 15;
  const int cnt = counts[e];
  if (mt * BM >= cnt) return;
  const int off = offsets[e];
  const int tid  = threadIdx.x;
  const int lane = tid & 63;
  const int wid  = tid >> 6;
  const int wr = wid >> 1;
  const int wc = wid & 1;

  u16* A_lds  = (u16*)smem;              // 16 KB, granule^(row&7)
  u16* B1_lds = (u16*)(smem + 16384);    // 8 KB  [n][granule^S(n)][8]
  u16* B3_lds = (u16*)(smem + 24576);    // 8 KB
  uint32_t* B1u = (uint32_t*)B1_lds;
  uint32_t* B3u = (uint32_t*)B3_lds;

  const u16* a_src[4];
#pragma unroll
  for (int i = 0; i < 4; ++i) {
    int row = (wid * 4 + i) * 8 + (lane >> 3);
    int mg = mt * BM + row;
    int mc = (mg < cnt) ? mg : (cnt - 1);
    int tok = token_list[off + mc];
    a_src[i] = Xb + (size_t)tok * HDIM + (((lane & 7) ^ (row & 7)) * 8);
  }

  // B staging thread map: p = tid>>3 -> k rows 2p,2p+1; cg = tid&7 -> cols
  // cg*8..+8. 8-lane groups read 256B contiguous per row (coalesced).
  const int p  = tid >> 3;
  const int cg = tid & 7;
  const int g  = p >> 2;       // k granule
  const int po = p & 3;        // u32 slot within granule
  const float* pw1 = w1 + (size_t)e * HDIM * FDIM + (size_t)(2 * p) * FDIM + nt * BN1 + cg * 8;
  const float* pw3 = w3 + (size_t)e * HDIM * FDIM + (size_t)(2 * p) * FDIM + nt * BN1 + cg * 8;

  f32x16 accg[2] = {};
  f32x16 accu[2] = {};
  bf16x8 af[2][4], bg[4], bu[4];
  float4 xa, xb_, xc, xd;

#define LOADBP(PW, T) { const float* q = (PW) + (size_t)(T) * BK * FDIM;       \
    xa = *(const float4*)(q);        xb_ = *(const float4*)(q + 4);            \
    xc = *(const float4*)(q + FDIM); xd  = *(const float4*)(q + FDIM + 4); }

  // write: n = cg*8+j, S(n) = cg^j; u32 idx = n*32 + ((g^S)*4) + po
#define CVTWP(Bu) {                                                            \
    Bu[(cg*8+0)*32 + ((g ^ cg ^ 0) * 4) + po] = pack2(xa.x, xc.x);             \
    Bu[(cg*8+1)*32 + ((g ^ cg ^ 1) * 4) + po] = pack2(xa.y, xc.y);             \
    Bu[(cg*8+2)*32 + ((g ^ cg ^ 2) * 4) + po] = pack2(xa.z, xc.z);             \
    Bu[(cg*8+3)*32 + ((g ^ cg ^ 3) * 4) + po] = pack2(xa.w, xc.w);             \
    Bu[(cg*8+4)*32 + ((g ^ cg ^ 4) * 4) + po] = pack2(xb_.x, xd.x);            \
    Bu[(cg*8+5)*32 + ((g ^ cg ^ 5) * 4) + po] = pack2(xb_.y, xd.y);            \
    Bu[(cg*8+6)*32 + ((g ^ cg ^ 6) * 4) + po] = pack2(xb_.z, xd.z);            \
    Bu[(cg*8+7)*32 + ((g ^ cg ^ 7) * 4) + po] = pack2(xb_.w, xd.w); }

  // prologue: stage tile 0 (B via regs+cvt, A via glds16)
  LOADBP(pw1, 0); CVTWP(B1u);
  LOADBP(pw3, 0); CVTWP(B3u);
#pragma unroll
  for (int i = 0; i < 4; ++i) glds16(a_src[i], &A_lds[(wid * 4 + i) * 512]);

#pragma unroll 1
  for (int t = 0; t < NK1; ++t) {
    __syncthreads();                 // [bar1] tile t fully in LDS
    if (t + 1 < NK1) LOADBP(pw1, t + 1);   // B1(t+1) -> regs, hides under FRAGS+MFMA
    // FRAGS(t)
#pragma unroll
    for (int m = 0; m < 2; ++m) {
      int R = wr * 64 + m * 32 + (lane & 31);
#pragma unroll
      for (int kk = 0; kk < 4; ++kk) {
        int gl = kk * 2 + (lane >> 5);
        af[m][kk] = *(const bf16x8*)&A_lds[R * BK + ((gl ^ (R & 7)) * 8)];
      }
    }
    {
      int n = wc * 32 + (lane & 31);
      int S = ((n >> 3) ^ n) & 7;
#pragma unroll
      for (int kk = 0; kk < 4; ++kk) {
        int gl = kk * 2 + (lane >> 5);
        bg[kk] = *(const bf16x8*)&B1_lds[n * 64 + ((gl ^ S) * 8)];
        bu[kk] = *(const bf16x8*)&B3_lds[n * 64 + ((gl ^ S) * 8)];
      }
    }
    __syncthreads();                 // [bar2] all reads of tile t done
    if (t + 1 < NK1) {
      const size_t ks = (size_t)(t + 1) * BK;
#pragma unroll
      for (int i = 0; i < 4; ++i) glds16(a_src[i] + ks, &A_lds[(wid * 4 + i) * 512]);
    }
    // MFMA half 1 (kk 0,1)
#pragma unroll
    for (int m = 0; m < 2; ++m)
#pragma unroll
      for (int kk = 0; kk < 2; ++kk) {
        accg[m] = __builtin_amdgcn_mfma_f32_32x32x16_bf16(af[m][kk], bg[kk], accg[m], 0, 0, 0);
        accu[m] = __builtin_amdgcn_mfma_f32_32x32x16_bf16(af[m][kk], bu[kk], accu[m], 0, 0, 0);
      }
    if (t + 1 < NK1) {
      CVTWP(B1u);                    // consume B1 regs (after bar2: safe)
      LOADBP(pw3, t + 1);            // B3(t+1) -> regs, hides under MFMA half 2
    }
    // MFMA half 2 (kk 2,3)
#pragma unroll
    for (int m = 0; m < 2; ++m)
#pragma unroll
      for (int kk = 2; kk < 4; ++kk) {
        accg[m] = __builtin_amdgcn_mfma_f32_32x32x16_bf16(af[m][kk], bg[kk], accg[m], 0, 0, 0);
        accu[m] = __builtin_amdgcn_mfma_f32_32x32x16_bf16(af[m][kk], bu[kk], accu[m], 0, 0, 0);
      }
    if (t + 1 < NK1) CVTWP(B3u);
  }
#undef LOADBP
#undef CVTWP

  // epilogue. 32x32 C/D: col=lane&31, row=(reg&3)+8*(reg>>2)+4*(lane>>5)
  const int fcol = nt * BN1 + wc * 32 + (lane & 31);
#pragma unroll
  for (int m = 0; m < 2; ++m) {
    int base = mt * BM + wr * 64 + m * 32 + 4 * (lane >> 5);
#pragma unroll
    for (int reg = 0; reg < 16; ++reg) {
      int mg = base + (reg & 3) + 8 * (reg >> 2);
      if (mg < cnt) {
        int slot = off + mg;
        float wgt = slot_w[slot];
        float gv = accg[m][reg];
        float uv = accu[m][reg];
        float sv = gv / (1.f + __expf(-gv));
        act[(size_t)slot * FDIM + fcol] = f2bf(sv * uv * wgt);
      }
    }
  }
}

// ---------------------------------------------------------------------------
// GEMM2 (R12-verbatim): y += act @ w2 (blob). BM=128 BN=128 BK=64, wave tile
// 64x64, single-buffer 2-barrier schedule, 3 blocks/CU.
// ---------------------------------------------------------------------------
__global__ __launch_bounds__(NTHR, 3)
void gemm2_kernel(const u16* __restrict__ act,
                  const u16* __restrict__ w2b,   // tiled [e][nt32][kt16][4096]
                  const int* __restrict__ token_list,
                  const int* __restrict__ counts,
                  const int* __restrict__ offsets,
                  float* __restrict__ y) {
  const int bid = blockIdx.x;
  const int e  = bid >> 8;
  const int mt = (bid >> 4) & 15;
  const int nt = bid & 15;
  const int cnt = counts[e];
  if (mt * BM >= cnt) return;
  const int off = offsets[e];
  const int tid  = threadIdx.x;
  const int lane = tid & 63;
  const int wid  = tid >> 6;
  const int wr = wid >> 1;
  const int wc = wid & 1;

  __shared__ u16 A_lds[BM * BK];     // 16 KB
  __shared__ u16 B_lds[BN2 * BK];    // 16 KB (two tiles of 4096)

  const u16* a_src[4];
  const u16* b_src[4];
#pragma unroll
  for (int i = 0; i < 4; ++i) {
    int row = (wid * 4 + i) * 8 + (lane >> 3);
    int mg = mt * BM + row;
    int mc = (mg < cnt) ? mg : (cnt - 1);
    a_src[i] = act + (size_t)(off + mc) * FDIM + (((lane & 7) ^ (row & 7)) * 8);
    int c = wid * 4 + i;
    size_t tbase = ((size_t)(e * 32 + nt * 2 + (c >> 3)) * 16) * TILE_E;
    b_src[i] = w2b + tbase + (c & 7) * 512 + lane * 8;
  }

  f32x16 acc[2][2] = {};

#pragma unroll
  for (int i = 0; i < 4; ++i) {
    glds16(a_src[i], &A_lds[(wid * 4 + i) * 512]);
    glds16(b_src[i], &B_lds[(wid * 4 + i) * 512]);
  }

#pragma unroll 1
  for (int t = 0; t < NK2; ++t) {
    __syncthreads();
    bf16x8 af[2][4], bb[2][4];
#pragma unroll
    for (int m = 0; m < 2; ++m) {
      int R = wr * 64 + m * 32 + (lane & 31);
#pragma unroll
      for (int kk = 0; kk < 4; ++kk) {
        int gl = kk * 2 + (lane >> 5);
        af[m][kk] = *(const bf16x8*)&A_lds[R * BK + ((gl ^ (R & 7)) * 8)];
      }
    }
#pragma unroll
    for (int n = 0; n < 2; ++n) {
      int R = wc * 64 + n * 32 + (lane & 31);
      int base = (R >> 6) * TILE_E + (R & 63) * 16 + (((lane >> 5) ^ ((R >> 2) & 1)) * 8);
#pragma unroll
      for (int kk = 0; kk < 4; ++kk)
        bb[n][kk] = *(const bf16x8*)&B_lds[base + kk * 1024];
    }
    __syncthreads();
    if (t + 1 < NK2) {
      const size_t ks = (size_t)(t + 1) * BK;
      const size_t kb = (size_t)(t + 1) * TILE_E;
#pragma unroll
      for (int i = 0; i < 4; ++i) {
        glds16(a_src[i] + ks, &A_lds[(wid * 4 + i) * 512]);
        glds16(b_src[i] + kb, &B_lds[(wid * 4 + i) * 512]);
      }
    }
#pragma unroll
    for (int kk = 0; kk < 4; ++kk)
#pragma unroll
      for (int m = 0; m < 2; ++m)
#pragma unroll
        for (int n = 0; n < 2; ++n)
          acc[m][n] = __builtin_amdgcn_mfma_f32_32x32x16_bf16(af[m][kk], bb[n][kk], acc[m][n], 0, 0, 0);
  }

#pragma unroll
  for (int m = 0; m < 2; ++m) {
    int base = mt * BM + wr * 64 + m * 32 + 4 * (lane >> 5);
#pragma unroll
    for (int reg = 0; reg < 16; ++reg) {
      int mg = base + (reg & 3) + 8 * (reg >> 2);
      if (mg < cnt) {
        int slot = off + mg;
        int tok = token_list[slot];
#pragma unroll
        for (int n = 0; n < 2; ++n) {
          int hcol = nt * BN2 + wc * 64 + n * 32 + (lane & 31);
          unsafeAtomicAdd(y + (size_t)tok * HDIM + hcol, acc[m][n][reg]);
        }
      }
    }
  }
}

// ---------------------------------------------------------------------------
extern "C" void kernel_launch(void* const* d_in, const int* in_sizes, int n_in,
                              void* d_out, int out_size, void* d_ws, size_t ws_size,
                              hipStream_t stream) {
  (void)in_sizes; (void)n_in; (void)out_size; (void)ws_size;
  const float* hs     = (const float*)d_in[0];
  const float* logits = (const float*)d_in[1];
  const float* w1     = (const float*)d_in[2];
  const float* w3     = (const float*)d_in[3];
  const float* w2     = (const float*)d_in[4];
  float* y = (float*)d_out;

  uint8_t* ws = (uint8_t*)d_ws;
  int*   token_list = (int*)(ws);
  float* slot_w     = (float*)(ws + (16 << 10));
  int*   counts     = (int*)(ws + (32 << 10));
  int*   offsets    = (int*)(ws + (32 << 10) + 128);
  int*   cursor     = (int*)(ws + (32 << 10) + 256);
  int*   tok_e      = (int*)(ws + (33 << 10));
  float* tok_w      = (float*)(ws + (42 << 10));
  const size_t MB = 1 << 20;
  u16*   Xb  = (u16*)(ws + (64 << 10));                 // 8 MB
  u16*   act = (u16*)(ws + (64 << 10) + 8 * MB);        // 8 MB
  u16*   w2b = (u16*)(ws + (64 << 10) + 16 * MB);       // 32 MB tiled

  hipMemsetAsync(counts, 0, NEXP * sizeof(int), stream);
  route1_kernel<<<T_TOK / 256, 256, 0, stream>>>(logits, tok_e, tok_w, counts);
  route2_kernel<<<1, 64, 0, stream>>>(counts, offsets, cursor);
  route3_kernel<<<T_TOK / 256, 256, 0, stream>>>(tok_e, tok_w, cursor, token_list, slot_w);
  mega1_kernel<<<512, 256, 0, stream>>>((const float4*)hs, (ushort4*)Xb, (float4*)y);
  mega2_kernel<<<3072, 256, 0, stream>>>(w2, w2b, Xb, w1, w3,
                                         token_list, slot_w, counts, offsets, act);
  gemm2_kernel<<<GRID2K, NTHR, 0, stream>>>(act, w2b, token_list, counts, offsets, y);
}

// Round 15
// 173.203 us; speedup vs baseline: 1.2375x; 1.1458x over previous
//
#include <hip/hip_runtime.h>
#include <stdint.h>

#define T_TOK 2048
#define HDIM  2048
#define FDIM  1024
#define NEXP  8

#define BM   128
#define BK   64
#define NTHR 256
#define MT_MAX 16                 // 2048 / BM
#define BN1  64
#define BN2  128
#define NT1 (FDIM / BN1)          // 16
#define NT2 (HDIM / BN2)          // 16
#define NK1 (HDIM / BK)           // 32
#define NK2 (FDIM / BK)           // 16
#define GRID2K (NEXP * MT_MAX * NT2)  // 2048 (gemm2)
#define TILE_E 4096               // elems per 64x64 bf16 tile (8 KB)
#define SMEM_BYTES 36864

typedef unsigned short u16;
typedef __attribute__((ext_vector_type(16))) float f32x16;
typedef __attribute__((ext_vector_type(8))) short bf16x8;

__device__ __forceinline__ u16 f2bf(float f) {
  uint32_t u = __float_as_uint(f);
  u += 0x7FFFu + ((u >> 16) & 1u);   // RNE
  return (u16)(u >> 16);
}

__device__ __forceinline__ uint32_t pack2(float lo, float hi) {
  return (uint32_t)f2bf(lo) | ((uint32_t)f2bf(hi) << 16);
}

__device__ __forceinline__ void glds16(const u16* src, u16* dst) {
  __builtin_amdgcn_global_load_lds(
      (const __attribute__((address_space(1))) uint32_t*)src,
      (__attribute__((address_space(3))) uint32_t*)dst, 16, 0, 0);
}

// ---------------------------------------------------------------------------
// Routing (order-invariant y; see R2 notes).
// ---------------------------------------------------------------------------
__global__ void route1_kernel(const float* __restrict__ logits,
                              int* __restrict__ tok_e, float* __restrict__ tok_w,
                              int* __restrict__ counts) {
  __shared__ int lcnt[NEXP];
  const int tid = threadIdx.x;
  const int t = blockIdx.x * 256 + tid;
  if (tid < NEXP) lcnt[tid] = 0;
  __syncthreads();
  float l[NEXP];
#pragma unroll
  for (int e = 0; e < NEXP; ++e) l[e] = logits[t * NEXP + e];
  float m = l[0];
#pragma unroll
  for (int e = 1; e < NEXP; ++e) m = fmaxf(m, l[e]);
  float p[NEXP]; float s = 0.f;
#pragma unroll
  for (int e = 0; e < NEXP; ++e) { p[e] = __expf(l[e] - m); s += p[e]; }
  float inv = 1.f / s;
  int i0 = 0; float p0 = p[0];
#pragma unroll
  for (int e = 1; e < NEXP; ++e) if (p[e] > p0) { p0 = p[e]; i0 = e; }
  int i1 = -1; float p1 = -1.f;
#pragma unroll
  for (int e = 0; e < NEXP; ++e) if (e != i0 && p[e] > p1) { p1 = p[e]; i1 = e; }
  tok_e[t] = i0 | (i1 << 8);
  tok_w[t * 2]     = p0 * inv;
  tok_w[t * 2 + 1] = p1 * inv;
  atomicAdd(&lcnt[i0], 1);
  atomicAdd(&lcnt[i1], 1);
  __syncthreads();
  if (tid < NEXP) atomicAdd(&counts[tid], lcnt[tid]);
}

__global__ void route2_kernel(const int* __restrict__ counts,
                              int* __restrict__ offsets, int* __restrict__ cursor) {
  if (threadIdx.x == 0) {
    int s = 0;
    for (int e = 0; e < NEXP; ++e) { offsets[e] = s; cursor[e] = s; s += counts[e]; }
    offsets[NEXP] = s;
  }
}

__global__ void route3_kernel(const int* __restrict__ tok_e, const float* __restrict__ tok_w,
                              int* __restrict__ cursor,
                              int* __restrict__ token_list, float* __restrict__ slot_w) {
  __shared__ int lcnt[NEXP], lbase[NEXP];
  const int tid = threadIdx.x;
  const int t = blockIdx.x * 256 + tid;
  if (tid < NEXP) lcnt[tid] = 0;
  __syncthreads();
  int ee = tok_e[t];
  int e0 = ee & 255, e1 = ee >> 8;
  int li0 = atomicAdd(&lcnt[e0], 1);
  int li1 = atomicAdd(&lcnt[e1], 1);
  __syncthreads();
  if (tid < NEXP) lbase[tid] = atomicAdd(&cursor[tid], lcnt[tid]);
  __syncthreads();
  int s0 = lbase[e0] + li0;
  int s1 = lbase[e1] + li1;
  token_list[s0] = t; slot_w[s0] = tok_w[t * 2];
  token_list[s1] = t; slot_w[s1] = tok_w[t * 2 + 1];
}

// ---------------------------------------------------------------------------
// Weight conversion block: linear-read (64 KB seq), contiguous 2 KB runs out.
// Blob intra-tile order: [kq4][n64][k16], halves swapped by s(n)=(n>>2)&1.
// ---------------------------------------------------------------------------
__device__ __forceinline__ void wconv_block(const float* __restrict__ src,
                                            u16* __restrict__ dstb,
                                            int C, int NT, int NKT,
                                            int e, int r0, int c0, uint32_t* L) {
  const int t = threadIdx.x;
  const int p  = t >> 5;        // row-pair 0..7
  const int ln = t & 31;
  const float* row0 = src + (size_t)(r0 + 2 * p) * C + c0;
  const float* row1 = row0 + C;
  float4 f0[8], f1[8];
#pragma unroll
  for (int j = 0; j < 8; ++j) f0[j] = *(const float4*)(row0 + j * 128 + ln * 4);
#pragma unroll
  for (int j = 0; j < 8; ++j) f1[j] = *(const float4*)(row1 + j * 128 + ln * 4);
#pragma unroll
  for (int j = 0; j < 8; ++j) {
    int n = j * 128 + ln * 4;
    L[(n + 0) * 9 + p] = pack2(f0[j].x, f1[j].x);
    L[(n + 1) * 9 + p] = pack2(f0[j].y, f1[j].y);
    L[(n + 2) * 9 + p] = pack2(f0[j].z, f1[j].z);
    L[(n + 3) * 9 + p] = pack2(f0[j].w, f1[j].w);
  }
  __syncthreads();
  const int kt = r0 >> 6, kq = (r0 >> 4) & 3;
#pragma unroll
  for (int i = 0; i < 4; ++i) {
    int n = t * 4 + i;
    const uint32_t* a = &L[n * 9];
    uint4 lo = {a[0], a[1], a[2], a[3]};
    uint4 hi = {a[4], a[5], a[6], a[7]};
    int ng = c0 + n;
    int s = (n >> 2) & 1;
    u16* tb = dstb + (((size_t)e * NT + (ng >> 6)) * NKT + kt) * TILE_E
                   + kq * 1024 + (n & 63) * 16;
    *(uint4*)(tb + s * 8)       = lo;
    *(uint4*)(tb + (s ^ 1) * 8) = hi;
  }
}

// ---------------------------------------------------------------------------
// MEGA1: bid<2048: w1/w3 conversion; 2048..2304: x cvt; 2304..2560: y zero.
// ---------------------------------------------------------------------------
__global__ __launch_bounds__(256, 3)
void mega1_kernel(const float* __restrict__ w1, const float* __restrict__ w3,
                  u16* __restrict__ w1b, u16* __restrict__ w3b,
                  const float4* __restrict__ x, ushort4* __restrict__ xb,
                  float4* __restrict__ y4) {
  __shared__ __align__(16) uint8_t smem[SMEM_BYTES];
  const int bid = blockIdx.x;
  const int t = threadIdx.x;
  if (bid < 2048) {
    const int m = bid >> 10;
    const int r = bid & 1023;
    const int e = r >> 7;
    const int g = r & 127;
    const size_t msz = (size_t)HDIM * FDIM;
    wconv_block((m ? w3 : w1) + (size_t)e * msz, m ? w3b : w1b,
                FDIM, 16, 32, e, g * 16, 0, (uint32_t*)smem);
  } else if (bid < 2304) {
    int i = (bid - 2048) * 256 + t;
#pragma unroll
    for (int r = 0; r < 16; ++r, i += 65536) {
      float4 v = x[i];
      ushort4 o;
      o.x = f2bf(v.x); o.y = f2bf(v.y); o.z = f2bf(v.z); o.w = f2bf(v.w);
      xb[i] = o;
    }
  } else {
    int i = (bid - 2304) * 256 + t;
    float4 z = {0.f, 0.f, 0.f, 0.f};
#pragma unroll
    for (int r = 0; r < 16; ++r, i += 65536) y4[i] = z;
  }
}

// ---------------------------------------------------------------------------
// MEGA2 (dispatch-order flipped vs R12): bid<2048: gemm1 (starts at t=0,
// the long pole); bid>=2048: w2 conversion (backfills CUs freed by gemm1's
// early-exit blocks). gemm1 = R12-proven single-buffer 2-barrier schedule.
// ---------------------------------------------------------------------------
__global__ __launch_bounds__(256, 3)
void mega2_kernel(const float* __restrict__ w2, u16* __restrict__ w2b,
                  const u16* __restrict__ Xb,
                  const u16* __restrict__ w1b, const u16* __restrict__ w3b,
                  const int* __restrict__ token_list,
                  const float* __restrict__ slot_w,
                  const int* __restrict__ counts,
                  const int* __restrict__ offsets,
                  u16* __restrict__ act) {
  __shared__ __align__(16) uint8_t smem[SMEM_BYTES];
  const int bid = blockIdx.x;
  if (bid >= 2048) {
    const int r = bid - 2048;      // 0..1023
    const int e = r >> 7;
    const int rr = r & 127;
    const int g = rr & 63;
    const int half = rr >> 6;
    wconv_block(w2 + (size_t)e * HDIM * FDIM, w2b,
                HDIM, 32, 16, e, g * 16, half * 1024, (uint32_t*)smem);
    return;
  }
  const int gb = bid;
  const int e  = gb >> 8;
  const int mt = (gb >> 4) & 15;
  const int nt = gb & 15;
  const int cnt = counts[e];
  if (mt * BM >= cnt) return;
  const int off = offsets[e];
  const int tid  = threadIdx.x;
  const int lane = tid & 63;
  const int wid  = tid >> 6;
  const int wr = wid >> 1;
  const int wc = wid & 1;

  u16* A_lds  = (u16*)smem;              // 16 KB, granule^(row&7)
  u16* B1_lds = (u16*)(smem + 16384);    // 8 KB (blob order)
  u16* B3_lds = (u16*)(smem + 24576);    // 8 KB

  const u16* a_src[4];
#pragma unroll
  for (int i = 0; i < 4; ++i) {
    int row = (wid * 4 + i) * 8 + (lane >> 3);
    int mg = mt * BM + row;
    int mc = (mg < cnt) ? mg : (cnt - 1);
    int tok = token_list[off + mc];
    a_src[i] = Xb + (size_t)tok * HDIM + (((lane & 7) ^ (row & 7)) * 8);
  }
  const u16* b1_src[2];
  const u16* b3_src[2];
  {
    size_t tbase = ((size_t)(e * 16 + nt) * 32) * TILE_E;
#pragma unroll
    for (int i = 0; i < 2; ++i) {
      int c = wid * 2 + i;
      b1_src[i] = w1b + tbase + c * 512 + lane * 8;
      b3_src[i] = w3b + tbase + c * 512 + lane * 8;
    }
  }

  f32x16 accg[2] = {};
  f32x16 accu[2] = {};

#pragma unroll
  for (int i = 0; i < 4; ++i) glds16(a_src[i], &A_lds[(wid * 4 + i) * 512]);
#pragma unroll
  for (int i = 0; i < 2; ++i) {
    glds16(b1_src[i], &B1_lds[(wid * 2 + i) * 512]);
    glds16(b3_src[i], &B3_lds[(wid * 2 + i) * 512]);
  }

#pragma unroll 1
  for (int t = 0; t < NK1; ++t) {
    __syncthreads();
    bf16x8 af[2][4], bg[4], bu[4];
#pragma unroll
    for (int m = 0; m < 2; ++m) {
      int R = wr * 64 + m * 32 + (lane & 31);
#pragma unroll
      for (int kk = 0; kk < 4; ++kk) {
        int gl = kk * 2 + (lane >> 5);
        af[m][kk] = *(const bf16x8*)&A_lds[R * BK + ((gl ^ (R & 7)) * 8)];
      }
    }
    {
      int R = wc * 32 + (lane & 31);
      int base = R * 16 + (((lane >> 5) ^ ((R >> 2) & 1)) * 8);
#pragma unroll
      for (int kk = 0; kk < 4; ++kk) {
        bg[kk] = *(const bf16x8*)&B1_lds[base + kk * 1024];
        bu[kk] = *(const bf16x8*)&B3_lds[base + kk * 1024];
      }
    }
    __syncthreads();
    if (t + 1 < NK1) {
      const size_t ks = (size_t)(t + 1) * BK;
      const size_t kb = (size_t)(t + 1) * TILE_E;
#pragma unroll
      for (int i = 0; i < 4; ++i) glds16(a_src[i] + ks, &A_lds[(wid * 4 + i) * 512]);
#pragma unroll
      for (int i = 0; i < 2; ++i) {
        glds16(b1_src[i] + kb, &B1_lds[(wid * 2 + i) * 512]);
        glds16(b3_src[i] + kb, &B3_lds[(wid * 2 + i) * 512]);
      }
    }
#pragma unroll
    for (int m = 0; m < 2; ++m)
#pragma unroll
      for (int kk = 0; kk < 4; ++kk) {
        accg[m] = __builtin_amdgcn_mfma_f32_32x32x16_bf16(af[m][kk], bg[kk], accg[m], 0, 0, 0);
        accu[m] = __builtin_amdgcn_mfma_f32_32x32x16_bf16(af[m][kk], bu[kk], accu[m], 0, 0, 0);
      }
  }

  const int fcol = nt * BN1 + wc * 32 + (lane & 31);
#pragma unroll
  for (int m = 0; m < 2; ++m) {
    int base = mt * BM + wr * 64 + m * 32 + 4 * (lane >> 5);
#pragma unroll
    for (int reg = 0; reg < 16; ++reg) {
      int mg = base + (reg & 3) + 8 * (reg >> 2);
      if (mg < cnt) {
        int slot = off + mg;
        float wgt = slot_w[slot];
        float g = accg[m][reg];
        float u = accu[m][reg];
        float sv = g / (1.f + __expf(-g));
        act[(size_t)slot * FDIM + fcol] = f2bf(sv * u * wgt);
      }
    }
  }
}

// ---------------------------------------------------------------------------
// GEMM2 (R12-verbatim): y += act @ w2 (blob). BM=128 BN=128 BK=64, wave
// tile 64x64, single-buffer 2-barrier schedule, 3 blocks/CU.
// ---------------------------------------------------------------------------
__global__ __launch_bounds__(NTHR, 3)
void gemm2_kernel(const u16* __restrict__ act,
                  const u16* __restrict__ w2b,   // tiled [e][nt32][kt16][4096]
                  const int* __restrict__ token_list,
                  const int* __restrict__ counts,
                  const int* __restrict__ offsets,
                  float* __restrict__ y) {
  const int bid = blockIdx.x;
  const int e  = bid >> 8;
  const int mt = (bid >> 4) & 15;
  const int nt = bid & 15;
  const int cnt = counts[e];
  if (mt * BM >= cnt) return;
  const int off = offsets[e];
  const int tid  = threadIdx.x;
  const int lane = tid & 63;
  const int wid  = tid >> 6;
  const int wr = wid >> 1;
  const int wc = wid & 1;

  __shared__ u16 A_lds[BM * BK];     // 16 KB
  __shared__ u16 B_lds[BN2 * BK];    // 16 KB (two tiles of 4096)

  const u16* a_src[4];
  const u16* b_src[4];
#pragma unroll
  for (int i = 0; i < 4; ++i) {
    int row = (wid * 4 + i) * 8 + (lane >> 3);
    int mg = mt * BM + row;
    int mc = (mg < cnt) ? mg : (cnt - 1);
    a_src[i] = act + (size_t)(off + mc) * FDIM + (((lane & 7) ^ (row & 7)) * 8);
    int c = wid * 4 + i;
    size_t tbase = ((size_t)(e * 32 + nt * 2 + (c >> 3)) * 16) * TILE_E;
    b_src[i] = w2b + tbase + (c & 7) * 512 + lane * 8;
  }

  f32x16 acc[2][2] = {};

#pragma unroll
  for (int i = 0; i < 4; ++i) {
    glds16(a_src[i], &A_lds[(wid * 4 + i) * 512]);
    glds16(b_src[i], &B_lds[(wid * 4 + i) * 512]);
  }

#pragma unroll 1
  for (int t = 0; t < NK2; ++t) {
    __syncthreads();
    bf16x8 af[2][4], bb[2][4];
#pragma unroll
    for (int m = 0; m < 2; ++m) {
      int R = wr * 64 + m * 32 + (lane & 31);
#pragma unroll
      for (int kk = 0; kk < 4; ++kk) {
        int gl = kk * 2 + (lane >> 5);
        af[m][kk] = *(const bf16x8*)&A_lds[R * BK + ((gl ^ (R & 7)) * 8)];
      }
    }
#pragma unroll
    for (int n = 0; n < 2; ++n) {
      int R = wc * 64 + n * 32 + (lane & 31);
      int base = (R >> 6) * TILE_E + (R & 63) * 16 + (((lane >> 5) ^ ((R >> 2) & 1)) * 8);
#pragma unroll
      for (int kk = 0; kk < 4; ++kk)
        bb[n][kk] = *(const bf16x8*)&B_lds[base + kk * 1024];
    }
    __syncthreads();
    if (t + 1 < NK2) {
      const size_t ks = (size_t)(t + 1) * BK;
      const size_t kb = (size_t)(t + 1) * TILE_E;
#pragma unroll
      for (int i = 0; i < 4; ++i) {
        glds16(a_src[i] + ks, &A_lds[(wid * 4 + i) * 512]);
        glds16(b_src[i] + kb, &B_lds[(wid * 4 + i) * 512]);
      }
    }
#pragma unroll
    for (int kk = 0; kk < 4; ++kk)
#pragma unroll
      for (int m = 0; m < 2; ++m)
#pragma unroll
        for (int n = 0; n < 2; ++n)
          acc[m][n] = __builtin_amdgcn_mfma_f32_32x32x16_bf16(af[m][kk], bb[n][kk], acc[m][n], 0, 0, 0);
  }

#pragma unroll
  for (int m = 0; m < 2; ++m) {
    int base = mt * BM + wr * 64 + m * 32 + 4 * (lane >> 5);
#pragma unroll
    for (int reg = 0; reg < 16; ++reg) {
      int mg = base + (reg & 3) + 8 * (reg >> 2);
      if (mg < cnt) {
        int slot = off + mg;
        int tok = token_list[slot];
#pragma unroll
        for (int n = 0; n < 2; ++n) {
          int hcol = nt * BN2 + wc * 64 + n * 32 + (lane & 31);
          unsafeAtomicAdd(y + (size_t)tok * HDIM + hcol, acc[m][n][reg]);
        }
      }
    }
  }
}

// ---------------------------------------------------------------------------
extern "C" void kernel_launch(void* const* d_in, const int* in_sizes, int n_in,
                              void* d_out, int out_size, void* d_ws, size_t ws_size,
                              hipStream_t stream) {
  (void)in_sizes; (void)n_in; (void)out_size; (void)ws_size;
  const float* hs     = (const float*)d_in[0];
  const float* logits = (const float*)d_in[1];
  const float* w1     = (const float*)d_in[2];
  const float* w3     = (const float*)d_in[3];
  const float* w2     = (const float*)d_in[4];
  float* y = (float*)d_out;

  uint8_t* ws = (uint8_t*)d_ws;
  int*   token_list = (int*)(ws);
  float* slot_w     = (float*)(ws + (16 << 10));
  int*   counts     = (int*)(ws + (32 << 10));
  int*   offsets    = (int*)(ws + (32 << 10) + 128);
  int*   cursor     = (int*)(ws + (32 << 10) + 256);
  int*   tok_e      = (int*)(ws + (33 << 10));
  float* tok_w      = (float*)(ws + (42 << 10));
  const size_t MB = 1 << 20;
  u16*   Xb  = (u16*)(ws + (64 << 10));                 // 8 MB
  u16*   act = (u16*)(ws + (64 << 10) + 8 * MB);        // 8 MB
  u16*   w1b = (u16*)(ws + (64 << 10) + 16 * MB);       // 32 MB tiled
  u16*   w3b = (u16*)(ws + (64 << 10) + 48 * MB);       // 32 MB tiled
  u16*   w2b = (u16*)(ws + (64 << 10) + 80 * MB);       // 32 MB tiled

  hipMemsetAsync(counts, 0, NEXP * sizeof(int), stream);
  route1_kernel<<<T_TOK / 256, 256, 0, stream>>>(logits, tok_e, tok_w, counts);
  route2_kernel<<<1, 64, 0, stream>>>(counts, offsets, cursor);
  route3_kernel<<<T_TOK / 256, 256, 0, stream>>>(tok_e, tok_w, cursor, token_list, slot_w);
  mega1_kernel<<<2560, 256, 0, stream>>>(w1, w3, w1b, w3b,
                                         (const float4*)hs, (ushort4*)Xb, (float4*)y);
  mega2_kernel<<<3072, 256, 0, stream>>>(w2, w2b, Xb, w1b, w3b,
                                         token_list, slot_w, counts, offsets, act);
  gemm2_kernel<<<GRID2K, NTHR, 0, stream>>>(act, w2b, token_list, counts, offsets, y);
}